// Round 9
// baseline (325.109 us; speedup 1.0000x reference)
//
#include <hip/hip_runtime.h>

#define NN 4096
#define R_RANK 10

typedef __bf16 bf16x8 __attribute__((ext_vector_type(8)));
typedef float floatx4 __attribute__((ext_vector_type(4)));

__device__ __forceinline__ unsigned short f2bf(float f) {
    union { float f; unsigned int u; } v; v.f = f;
    unsigned int r = v.u + 0x7FFFu + ((v.u >> 16) & 1u);   // RNE
    return (unsigned short)(r >> 16);
}
// async global->LDS, 16B per lane; LDS dest = wave-uniform base + lane*16
__device__ __forceinline__ void gll16(const void* g, void* l) {
    __builtin_amdgcn_global_load_lds(
        (const __attribute__((address_space(1))) unsigned int*)g,
        (__attribute__((address_space(3))) unsigned int*)l, 16, 0, 0);
}
template<int N>
__device__ __forceinline__ void wait_vm() {
    if constexpr (N == 0)       asm volatile("s_waitcnt vmcnt(0)" ::: "memory");
    else if constexpr (N == 3)  asm volatile("s_waitcnt vmcnt(3)" ::: "memory");
    else if constexpr (N == 4)  asm volatile("s_waitcnt vmcnt(4)" ::: "memory");
    else if constexpr (N == 6)  asm volatile("s_waitcnt vmcnt(6)" ::: "memory");
    else if constexpr (N == 8)  asm volatile("s_waitcnt vmcnt(8)" ::: "memory");
    else static_assert(N < 0, "add vmcnt literal");
}
#define SB __builtin_amdgcn_sched_barrier(0)

// ---------------------------------------------------------------------------
// Adjacency: row stats (4 rows/block; zeroes deg+pooled) -> col degree -> AnT
// ---------------------------------------------------------------------------
__global__ __launch_bounds__(256) void row_stats_kernel(
    const float* __restrict__ nv1, const float* __restrict__ nv2,
    float* __restrict__ rowmax, float* __restrict__ rowsum,
    float* __restrict__ deg, float* __restrict__ pooled)
{
    const int i0 = blockIdx.x * 4;
    const int tid = threadIdx.x;
    if (blockIdx.x < 16) deg[blockIdx.x * 256 + tid] = 0.f;
    if (blockIdx.x >= 16 && blockIdx.x < 18) pooled[(blockIdx.x - 16) * 256 + tid] = 0.f;
    __shared__ float a[4][R_RANK];
    if (tid < 4 * R_RANK) a[tid / R_RANK][tid % R_RANK] = nv1[i0 * R_RANK + tid];
    __syncthreads();

    float s[4][16];
    float mx[4] = {0.f, 0.f, 0.f, 0.f};   // relu >= 0
    #pragma unroll
    for (int t = 0; t < 16; ++t) {
        const int j = t * 256 + tid;
        float v[R_RANK];
        #pragma unroll
        for (int r = 0; r < R_RANK; ++r) v[r] = nv2[r * NN + j];
        #pragma unroll
        for (int q = 0; q < 4; ++q) {
            float acc = 0.f;
            #pragma unroll
            for (int r = 0; r < R_RANK; ++r) acc = fmaf(a[q][r], v[r], acc);
            acc = fmaxf(acc, 0.f);
            s[q][t] = acc;
            mx[q] = fmaxf(mx[q], acc);
        }
    }
    __shared__ float red[4][4];
    #pragma unroll
    for (int q = 0; q < 4; ++q) {
        float m = mx[q];
        #pragma unroll
        for (int off = 32; off > 0; off >>= 1) m = fmaxf(m, __shfl_down(m, off, 64));
        if ((tid & 63) == 0) red[q][tid >> 6] = m;
    }
    __syncthreads();
    #pragma unroll
    for (int q = 0; q < 4; ++q)
        mx[q] = fmaxf(fmaxf(red[q][0], red[q][1]), fmaxf(red[q][2], red[q][3]));
    __syncthreads();
    float sm[4] = {0.f, 0.f, 0.f, 0.f};
    #pragma unroll
    for (int t = 0; t < 16; ++t)
        #pragma unroll
        for (int q = 0; q < 4; ++q) sm[q] += __expf(s[q][t] - mx[q]);
    #pragma unroll
    for (int q = 0; q < 4; ++q) {
        float m = sm[q];
        #pragma unroll
        for (int off = 32; off > 0; off >>= 1) m += __shfl_down(m, off, 64);
        if ((tid & 63) == 0) red[q][tid >> 6] = m;
    }
    __syncthreads();
    if (tid < 4) {
        rowmax[i0 + tid] = mx[tid];
        rowsum[i0 + tid] = red[tid][0] + red[tid][1] + red[tid][2] + red[tid][3];
    }
}

// col degree: deg[j] += sum_{i in chunk} exp(relu(nv1_i . nv2_j) - rm_i)/rs_i
__global__ __launch_bounds__(256) void col_sum_kernel(
    const float* __restrict__ nv1, const float* __restrict__ nv2,
    const float* __restrict__ rowmax, const float* __restrict__ rowsum,
    float* __restrict__ deg)
{
    const int tid = threadIdx.x;
    const int j = blockIdx.x * 256 + tid;
    const int i0 = blockIdx.y * 64;
    __shared__ float a[64][R_RANK];
    __shared__ float rm[64], rs[64];
    if (tid < 64) {
        rm[tid] = rowmax[i0 + tid];
        rs[tid] = 1.0f / rowsum[i0 + tid];
    }
    for (int t = tid; t < 64 * R_RANK; t += 256)
        a[t / R_RANK][t % R_RANK] = nv1[i0 * R_RANK + t];
    __syncthreads();

    float v[R_RANK];
    #pragma unroll
    for (int r = 0; r < R_RANK; ++r) v[r] = nv2[r * NN + j];
    float acc = 0.f;
    #pragma unroll 4
    for (int t = 0; t < 64; ++t) {
        float s = 0.f;
        #pragma unroll
        for (int r = 0; r < R_RANK; ++r) s = fmaf(a[t][r], v[r], s);
        s = fmaxf(s, 0.f);
        acc += __expf(s - rm[t]) * rs[t];
    }
    atomicAdd(&deg[j], acc);
}

__global__ __launch_bounds__(256) void an_build_kernel(
    const float* __restrict__ nv1, const float* __restrict__ nv2,
    const float* __restrict__ rowmax, const float* __restrict__ rowsum,
    const float* __restrict__ deg, unsigned short* __restrict__ AnT)
{
    const int tid = threadIdx.x;
    const int j = blockIdx.x * 256 + tid;
    const int i0 = blockIdx.y * 8;
    __shared__ float v2s[8][R_RANK];
    __shared__ float dis[8];
    if (tid < 8 * R_RANK) {
        const int r = tid / 8, t = tid % 8;
        v2s[t][r] = nv2[r * NN + i0 + t];
    }
    if (tid < 8) dis[tid] = rsqrtf(1.0f + deg[i0 + tid]);

    float a[R_RANK];
    #pragma unroll
    for (int r = 0; r < R_RANK; ++r) a[r] = nv1[j * R_RANK + r];
    const float rm = rowmax[j];
    const float rs = 1.0f / rowsum[j];
    const float dj = rsqrtf(1.0f + deg[j]);
    __syncthreads();

    #pragma unroll
    for (int t = 0; t < 8; ++t) {
        const int i = i0 + t;
        float s = 0.f;
        #pragma unroll
        for (int r = 0; r < R_RANK; ++r) s = fmaf(a[r], v2s[t][r], s);
        s = fmaxf(s, 0.f);
        const float adp = __expf(s - rm) * rs;
        const float val = (adp + ((i == j) ? 1.f : 0.f)) * dis[t] * dj;
        AnT[(size_t)i * NN + j] = f2bf(val);
    }
}

// ---------------------------------------------------------------------------
// prep: z=0 w_map^T, z=1 w1^T, z=2 w2^T (fp32 -> bf16 transposed), z=3 cvt x
// ---------------------------------------------------------------------------
__global__ __launch_bounds__(256) void prep_kernel(
    const float* __restrict__ x, const float* __restrict__ w_map,
    const float* __restrict__ w1, const float* __restrict__ w2,
    unsigned short* __restrict__ xb, unsigned short* __restrict__ wmT,
    unsigned short* __restrict__ w1T, unsigned short* __restrict__ w2T)
{
    const int z = blockIdx.z;
    const int tid = threadIdx.x;
    if (z == 3) {
        const int b = blockIdx.x + blockIdx.y * 32;
        const size_t base = (size_t)b * 4096 + (size_t)tid * 16;
        #pragma unroll
        for (int i = 0; i < 2; ++i) {
            const float4 a0 = *(const float4*)(x + base + i * 8);
            const float4 a1 = *(const float4*)(x + base + i * 8 + 4);
            ushort4 p, q;
            p.x = f2bf(a0.x); p.y = f2bf(a0.y); p.z = f2bf(a0.z); p.w = f2bf(a0.w);
            q.x = f2bf(a1.x); q.y = f2bf(a1.y); q.z = f2bf(a1.z); q.w = f2bf(a1.w);
            *(ushort4*)(xb + base + i * 8) = p;
            *(ushort4*)(xb + base + i * 8 + 4) = q;
        }
        return;
    }
    const float* W = (z == 0) ? w_map : (z == 1) ? w1 : w2;
    unsigned short* WT = (z == 0) ? wmT : (z == 1) ? w1T : w2T;
    const int CN = (z == 2) ? 512 : 1024;
    if (blockIdx.x * 32 >= CN) return;
    __shared__ float s[32][33];
    const int tx = tid & 31, ty = tid >> 5;
    const int r0 = blockIdx.y * 32, c0 = blockIdx.x * 32;
    #pragma unroll
    for (int i = 0; i < 4; ++i)
        s[ty + 8 * i][tx] = W[(size_t)(r0 + ty + 8 * i) * CN + c0 + tx];
    __syncthreads();
    #pragma unroll
    for (int i = 0; i < 4; ++i)
        WT[(size_t)(c0 + ty + 8 * i) * 1024 + r0 + tx] = f2bf(s[tx][ty + 8 * i]);
}

// ---------------------------------------------------------------------------
// 128x128 bf16 MFMA GEMM (BK=64, 8 waves 2x4, 4x2 frags). 2 LDS buffers
// (64 KB -> 2 blocks/CU capacity), depth-1 counted-vmcnt prefetch, raw
// barriers, XCD-chunked swizzle.
// OUTM: 0 = fp32 P[z][M][N]; 1 = bf16 [M][N] fused epilogue.
// EPI (OUTM==1): 0 none, 1 relu(x+bias), 2 bn(relu(x+bias)) col-indexed.
// ---------------------------------------------------------------------------
template<int OUTM, int EPI, int SK>
__global__ __launch_bounds__(512) void gemm_mfma(
    const unsigned short* __restrict__ A, const unsigned short* __restrict__ Bt,
    void* __restrict__ Out, const int M, const int N, const int K,
    const float* __restrict__ bias, const float* __restrict__ gamma,
    const float* __restrict__ beta, const float* __restrict__ mean,
    const float* __restrict__ var)
{
    __shared__ __align__(16) unsigned short As[2][8192];
    __shared__ __align__(16) unsigned short Bs[2][8192];
    const int tid = threadIdx.x;
    const int l = tid & 63, w = tid >> 6;       // 8 waves
    const int wy = w >> 2, wx = w & 3;          // 2x4 wave grid, 64x32 per wave
    const int lr = l & 15, lq = l >> 4;

    // XCD-chunked bijective swizzle (nwg % 8 == 0)
    const int gx = gridDim.x, gy = gridDim.y;
    int lin = blockIdx.x + gx * (blockIdx.y + gy * blockIdx.z);
    const int q = (gx * gy * gridDim.z) >> 3;
    lin = (lin & 7) * q + (lin >> 3);
    const int bx = lin % gx;
    const int by = (lin / gx) % gy;
    const int bz = lin / (gx * gy);

    const int row0 = by * 128, col0 = bx * 128;
    const int Kc = K / SK;
    const int kb = bz * Kc;
    const int nt = Kc >> 6;                      // K-tiles of 64

    const unsigned short* Ag0 = A + (size_t)(row0 + w * 16 + lr) * K + kb + lq * 8;
    const unsigned short* Bg0 = Bt + (size_t)(col0 + w * 16 + lr) * K + kb + lq * 8;

    floatx4 acc[4][2];
    #pragma unroll
    for (int i = 0; i < 4; ++i)
        #pragma unroll
        for (int j = 0; j < 2; ++j) acc[i][j] = (floatx4){0.f, 0.f, 0.f, 0.f};

    #define STAGE(b, t)                                                         \
    {                                                                           \
        char* Aw = (char*)As[b] + w * 1024;                                     \
        char* Bw = (char*)Bs[b] + w * 1024;                                     \
        const int kk = (t) * 64;                                                \
        gll16(Ag0 + kk,      Aw);                                               \
        gll16(Ag0 + kk + 32, Aw + 8192);                                        \
        gll16(Bg0 + kk,      Bw);                                               \
        gll16(Bg0 + kk + 32, Bw + 8192);                                        \
    }

    STAGE(0, 0)
    for (int t = 0; t < nt; ++t) {
        if (t + 1 < nt) {
            STAGE((t + 1) & 1, t + 1)
            wait_vm<4>();                   // retire tile t's 4; t+1's fly
        } else {
            wait_vm<0>();
        }
        SB; __builtin_amdgcn_s_barrier(); SB;   // buf t ready (RAW)

        const char* Afr = (const char*)As[t & 1] + wy * 4096 + l * 16;
        const char* Bfr = (const char*)Bs[t & 1] + wx * 2048 + l * 16;
        #pragma unroll
        for (int h = 0; h < 2; ++h) {
            bf16x8 af[4], bf[2];
            #pragma unroll
            for (int i = 0; i < 4; ++i) af[i] = *(const bf16x8*)(Afr + h * 8192 + i * 1024);
            #pragma unroll
            for (int j = 0; j < 2; ++j) bf[j] = *(const bf16x8*)(Bfr + h * 8192 + j * 1024);
            #pragma unroll
            for (int mf = 0; mf < 4; ++mf)
                #pragma unroll
                for (int nf = 0; nf < 2; ++nf)
                    acc[mf][nf] = __builtin_amdgcn_mfma_f32_16x16x32_bf16(
                        af[mf], bf[nf], acc[mf][nf], 0, 0, 0);
        }
        SB; __builtin_amdgcn_s_barrier(); SB;   // reads done (WAR)
    }
    #undef STAGE

    const int gr0 = row0 + wy * 64 + lq * 4;
    const int gc0 = col0 + wx * 32 + lr;
    if constexpr (OUTM == 0) {
        float* Pz = (float*)Out + (size_t)bz * M * N;
        #pragma unroll
        for (int mf = 0; mf < 4; ++mf) {
            const int gr = gr0 + mf * 16;
            #pragma unroll
            for (int nf = 0; nf < 2; ++nf) {
                const int gc = gc0 + nf * 16;
                #pragma unroll
                for (int r = 0; r < 4; ++r)
                    Pz[(size_t)(gr + r) * N + gc] = acc[mf][nf][r];
            }
        }
    } else {
        unsigned short* O = (unsigned short*)Out;
        #pragma unroll
        for (int nf = 0; nf < 2; ++nf) {
            const int gc = gc0 + nf * 16;
            float bb = 0.f, sc = 1.f, sh = 0.f;
            if constexpr (EPI >= 1) bb = bias[gc];
            if constexpr (EPI == 2) {
                sc = gamma[gc] * rsqrtf(var[gc] + 1e-5f);
                sh = beta[gc] - mean[gc] * sc;
            }
            #pragma unroll
            for (int mf = 0; mf < 4; ++mf) {
                const int gr = gr0 + mf * 16;
                #pragma unroll
                for (int r = 0; r < 4; ++r) {
                    float xv = acc[mf][nf][r];
                    if constexpr (EPI >= 1) xv = fmaxf(xv + bb, 0.f);
                    if constexpr (EPI == 2) xv = fmaf(xv, sc, sh);
                    O[(size_t)(gr + r) * N + gc] = f2bf(xv);
                }
            }
        }
    }
}

// ---------------------------------------------------------------------------
// Big-tile bf16 MFMA GEMM, BM=256 x BN=128, BK=32, 8 waves (2x4), per-wave
// 128x32 (8x2 frags). Frag-ordered conflict-free LDS, 3 buffers (72 KB ->
// 2 blocks/CU), depth-2 counted-vmcnt prefetch, raw barriers, XCD swizzle.
// fp32 partials P[z][M][N]. __launch_bounds__(512,4) caps VGPR at 128 so
// 16 waves/CU (2 blocks) are resident -> cross-block staging/compute overlap.
// ---------------------------------------------------------------------------
template<int BM, int BN, int SK>
__global__ __launch_bounds__(512, 4) void gemm_big(
    const unsigned short* __restrict__ A, const unsigned short* __restrict__ Bt,
    float* __restrict__ P, const int M, const int N, const int K)
{
    constexpr int MR = BM / 32;           // m-frags per wave (8)
    constexpr int NRF = BN / 64;          // n-frags per wave (2)
    constexpr int MH = MR / 2;
    constexpr int NA = BM / 128;          // A gll16 per wave per tile (2)
    constexpr int NB = BN / 128;          // B gll16 per wave per tile (1)
    constexpr int LPT = NA + NB;          // 3
    constexpr int ABYTES = BM * 64;       // A section bytes per buffer (16 KB)
    __shared__ __align__(16) unsigned short L[3][(BM + BN) * 32];   // 3 x 24 KB
    const int tid = threadIdx.x;
    const int l = tid & 63, w = tid >> 6;
    const int wy = w >> 2, wx = w & 3;
    const int lr = l & 15, lq = l >> 4;

    const int gx = gridDim.x, gy = gridDim.y;
    int lin = blockIdx.x + gx * (blockIdx.y + gy * blockIdx.z);
    const int q = (gx * gy * gridDim.z) >> 3;   // nwg % 8 == 0
    lin = (lin & 7) * q + (lin >> 3);
    const int bx = lin % gx;
    const int by = (lin / gx) % gy;
    const int bz = lin / (gx * gy);

    const int row0 = by * BM, col0 = bx * BN;
    const int Kc = K / SK, kb = bz * Kc;
    const int nt = Kc >> 5;                     // BK=32 tiles (>= 16 here)

    const unsigned short* Ag = A + (size_t)(row0 + w * (BM / 8) + lr) * K + kb + lq * 8;
    const unsigned short* Bg = Bt + (size_t)(col0 + w * (BN / 8) + lr) * K + kb + lq * 8;

    floatx4 acc[MR][NRF];
    #pragma unroll
    for (int i = 0; i < MR; ++i)
        #pragma unroll
        for (int j = 0; j < NRF; ++j) acc[i][j] = (floatx4){0.f, 0.f, 0.f, 0.f};

    #define STAGEB(b, t)                                                        \
    {                                                                           \
        char* Ld = (char*)L[b];                                                 \
        const int kk = (t) * 32;                                                \
        _Pragma("unroll")                                                       \
        for (int s = 0; s < NA; ++s)                                            \
            gll16(Ag + (size_t)(s * 16) * K + kk, Ld + (w * NA + s) * 1024);    \
        _Pragma("unroll")                                                       \
        for (int s = 0; s < NB; ++s)                                            \
            gll16(Bg + (size_t)(s * 16) * K + kk,                               \
                  Ld + ABYTES + (w * NB + s) * 1024);                           \
    }

    STAGEB(0, 0)
    STAGEB(1, 1)
    int b0 = 0, b1 = 1, b2 = 2;                 // rotating buffer indices
    for (int t = 0; t < nt; ++t) {
        if (t + 2 < nt) {
            STAGEB(b2, t + 2)
            wait_vm<2 * LPT>();                 // tile t retired; t+1,t+2 fly
        } else if (t + 1 < nt) {
            wait_vm<LPT>();
        } else {
            wait_vm<0>();
        }
        SB; __builtin_amdgcn_s_barrier(); SB;   // buf b0 published (RAW)

        // A section: wave-row wy owns MR 1KB chunks at offset wy*MR*1024
        const char* Ab = (const char*)L[b0] + wy * (MR * 1024) + l * 16;
        const char* Bb = (const char*)L[b0] + ABYTES + wx * (NRF * 1024) + l * 16;

        bf16x8 bf[NRF], af0[MH];
        #pragma unroll
        for (int j = 0; j < NRF; ++j) bf[j] = *(const bf16x8*)(Bb + j * 1024);
        #pragma unroll
        for (int i = 0; i < MH; ++i) af0[i] = *(const bf16x8*)(Ab + i * 1024);
        __builtin_amdgcn_s_setprio(1);
        #pragma unroll
        for (int mf = 0; mf < MH; ++mf)
            #pragma unroll
            for (int nf = 0; nf < NRF; ++nf)
                acc[mf][nf] = __builtin_amdgcn_mfma_f32_16x16x32_bf16(
                    af0[mf], bf[nf], acc[mf][nf], 0, 0, 0);
        __builtin_amdgcn_s_setprio(0);
        bf16x8 af1[MH];
        #pragma unroll
        for (int i = 0; i < MH; ++i) af1[i] = *(const bf16x8*)(Ab + (MH + i) * 1024);
        __builtin_amdgcn_s_setprio(1);
        #pragma unroll
        for (int mf = 0; mf < MH; ++mf)
            #pragma unroll
            for (int nf = 0; nf < NRF; ++nf)
                acc[MH + mf][nf] = __builtin_amdgcn_mfma_f32_16x16x32_bf16(
                    af1[mf], bf[nf], acc[MH + mf][nf], 0, 0, 0);
        __builtin_amdgcn_s_setprio(0);
        SB; __builtin_amdgcn_s_barrier(); SB;   // all reads done (WAR)
        const int tmp = b0; b0 = b1; b1 = b2; b2 = tmp;
    }
    #undef STAGEB

    float* Pz = P + (size_t)bz * M * N;
    const int gr0 = row0 + wy * (BM / 2) + lq * 4;
    const int gc0 = col0 + wx * (BN / 4) + lr;
    #pragma unroll
    for (int mf = 0; mf < MR; ++mf) {
        const int gr = gr0 + mf * 16;
        #pragma unroll
        for (int nf = 0; nf < NRF; ++nf) {
            const int gc = gc0 + nf * 16;
            #pragma unroll
            for (int r = 0; r < 4; ++r)
                Pz[(size_t)(gr + r) * N + gc] = acc[mf][nf][r];
        }
    }
}

// ---------------------------------------------------------------------------
// Split-K reduce + epilogue -> bf16. EPI: 0 none, 2 bn(relu(x+b)) col-indexed.
// ---------------------------------------------------------------------------
template<int EPI, int S, int NC>
__global__ __launch_bounds__(256) void reduce_k(
    const float* __restrict__ P, unsigned short* __restrict__ out, const int MN,
    const float* __restrict__ bias, const float* __restrict__ gamma,
    const float* __restrict__ beta, const float* __restrict__ mean,
    const float* __restrict__ var)
{
    const int idx = blockIdx.x * 256 + threadIdx.x;   // float4 index
    const int n4 = MN >> 2;
    const float4* Pv = (const float4*)P;
    float4 v = Pv[idx];
    #pragma unroll
    for (int z = 1; z < S; ++z) {
        const float4 t = Pv[idx + (size_t)z * n4];
        v.x += t.x; v.y += t.y; v.z += t.z; v.w += t.w;
    }
    float vals[4] = {v.x, v.y, v.z, v.w};
    if constexpr (EPI >= 1) {
        const int c0 = (idx << 2) & (NC - 1);
        const float4 b4 = *(const float4*)(bias + c0);
        const float bb[4] = {b4.x, b4.y, b4.z, b4.w};
        float sc[4], sh[4];
        if constexpr (EPI == 2) {
            const float4 g4 = *(const float4*)(gamma + c0);
            const float4 e4 = *(const float4*)(beta + c0);
            const float4 m4 = *(const float4*)(mean + c0);
            const float4 v4 = *(const float4*)(var + c0);
            const float gg[4] = {g4.x, g4.y, g4.z, g4.w};
            const float ee[4] = {e4.x, e4.y, e4.z, e4.w};
            const float mm[4] = {m4.x, m4.y, m4.z, m4.w};
            const float vv[4] = {v4.x, v4.y, v4.z, v4.w};
            #pragma unroll
            for (int j = 0; j < 4; ++j) {
                sc[j] = gg[j] * rsqrtf(vv[j] + 1e-5f);
                sh[j] = ee[j] - mm[j] * sc[j];
            }
        }
        #pragma unroll
        for (int j = 0; j < 4; ++j) {
            float xv = fmaxf(vals[j] + bb[j], 0.f);
            if constexpr (EPI == 2) xv = fmaf(xv, sc[j], sh[j]);
            vals[j] = xv;
        }
    }
    ushort4 p;
    p.x = f2bf(vals[0]); p.y = f2bf(vals[1]); p.z = f2bf(vals[2]); p.w = f2bf(vals[3]);
    *(ushort4*)(out + ((size_t)idx << 2)) = p;
}

// ---------------------------------------------------------------------------
// Split-K reduce + bn2(relu(x+b)) + mean-pool (h2 never materialized).
// P[z][512][4096]; params row(=channel)-indexed; atomicAdd per-block sums.
// ---------------------------------------------------------------------------
template<int S>
__global__ __launch_bounds__(256) void reduce_pool_kernel(
    const float* __restrict__ P, float* __restrict__ pooled,
    const float* __restrict__ bias, const float* __restrict__ gamma,
    const float* __restrict__ beta, const float* __restrict__ mean,
    const float* __restrict__ var)
{
    const int idx = blockIdx.x * 256 + threadIdx.x;   // float4 index
    const int row = blockIdx.x >> 2;                  // 4096 floats = 1024 f4 per row
    constexpr int n4 = 512 * 4096 / 4;
    const float4* Pv = (const float4*)P;
    float4 v = Pv[idx];
    #pragma unroll
    for (int z = 1; z < S; ++z) {
        const float4 t = Pv[idx + (size_t)z * n4];
        v.x += t.x; v.y += t.y; v.z += t.z; v.w += t.w;
    }
    const float b0 = bias[row];
    const float sc = gamma[row] * rsqrtf(var[row] + 1e-5f);
    const float sh = beta[row] - mean[row] * sc;
    float s = 0.f;
    const float vals[4] = {v.x, v.y, v.z, v.w};
    #pragma unroll
    for (int j = 0; j < 4; ++j)
        s += fmaf(fmaxf(vals[j] + b0, 0.f), sc, sh);
    #pragma unroll
    for (int off = 32; off > 0; off >>= 1) s += __shfl_down(s, off, 64);
    __shared__ float red[4];
    if ((threadIdx.x & 63) == 0) red[threadIdx.x >> 6] = s;
    __syncthreads();
    if (threadIdx.x == 0)
        atomicAdd(&pooled[row], red[0] + red[1] + red[2] + red[3]);
}

__global__ __launch_bounds__(512) void finalize_kernel(
    const float* __restrict__ pooled, const float* __restrict__ w_attn,
    const float* __restrict__ b_attn, float* __restrict__ out)
{
    const int c = threadIdx.x;
    __shared__ float red[512];
    const float p = pooled[c] * (1.0f / 4096.0f);
    red[c] = p * w_attn[c];
    __syncthreads();
    for (int s = 256; s > 0; s >>= 1) {
        if (c < s) red[c] += red[c + s];
        __syncthreads();
    }
    const float attn = 1.0f / (1.0f + __expf(-(red[0] + b_attn[0])));
    out[c] = p * attn;
}

// ---------------------------------------------------------------------------
extern "C" void kernel_launch(void* const* d_in, const int* in_sizes, int n_in,
                              void* d_out, int out_size, void* d_ws, size_t ws_size,
                              hipStream_t stream) {
    const float* x      = (const float*)d_in[0];
    const float* w_map  = (const float*)d_in[1];
    const float* b_map  = (const float*)d_in[2];
    const float* nv1    = (const float*)d_in[3];
    const float* nv2    = (const float*)d_in[4];
    const float* w1     = (const float*)d_in[5];
    const float* b1     = (const float*)d_in[6];
    const float* w2     = (const float*)d_in[7];
    const float* b2     = (const float*)d_in[8];
    const float* bn1_g  = (const float*)d_in[9];
    const float* bn1_b  = (const float*)d_in[10];
    const float* bn1_m  = (const float*)d_in[11];
    const float* bn1_v  = (const float*)d_in[12];
    const float* bn2_g  = (const float*)d_in[13];
    const float* bn2_b  = (const float*)d_in[14];
    const float* bn2_m  = (const float*)d_in[15];
    const float* bn2_v  = (const float*)d_in[16];
    const float* w_attn = (const float*)d_in[17];
    const float* b_attn = (const float*)d_in[18];
    float* out = (float*)d_out;

    const size_t MB = 1024 * 1024;
    // big: P gets 64 MB (G3 SK4, G5 SK8); small: P 32 MB (G3 SK2, G5 SK4)
    const bool big = ws_size >= 118 * MB;
    char* ws = (char*)d_ws;
    unsigned short* AnT = (unsigned short*)(ws);                  // [0,32M)
    float*          P   = (float*)(ws + 32 * MB);                 // 64M (big) / 32M
    char* B0 = big ? (ws + 96 * MB) : (ws + 64 * MB);
    unsigned short* xb  = (unsigned short*)(B0);                  // 8 MB, dead after G1
    unsigned short* t1T = (unsigned short*)(B0);                  //   reuse, dead after G3
    unsigned short* t2T = (unsigned short*)(B0);                  //   reuse after G3
    unsigned short* xm  = (unsigned short*)(B0 + 8 * MB);         // 8 MB, dead after G2
    unsigned short* h1  = (unsigned short*)(B0 + 8 * MB);         //   reuse, dead after G4
    unsigned short* wmT = (unsigned short*)(B0 + 16 * MB);        // 2 MB
    unsigned short* w1T = (unsigned short*)(B0 + 18 * MB);        // 2 MB
    unsigned short* w2T = (unsigned short*)(B0 + 20 * MB);        // 1 MB
    float* deg    = (float*)(B0 + 21 * MB);
    float* rowmax = deg + 4096;
    float* rowsum = rowmax + 4096;
    float* pooled = rowsum + 4096;

    // prep + adjacency
    prep_kernel<<<dim3(32, 32, 4), 256, 0, stream>>>(x, w_map, w1, w2, xb, wmT, w1T, w2T);
    row_stats_kernel<<<1024, 256, 0, stream>>>(nv1, nv2, rowmax, rowsum, deg, pooled);
    col_sum_kernel<<<dim3(16, 64), 256, 0, stream>>>(nv1, nv2, rowmax, rowsum, deg);
    an_build_kernel<<<dim3(16, 512), 256, 0, stream>>>(nv1, nv2, rowmax, rowsum, deg, AnT);

    // G1: xm = relu(x @ w_map + b_map)   M4096 N1024 K1024, fused epi
    gemm_mfma<1, 1, 1><<<dim3(8, 32, 1), 512, 0, stream>>>(xb, wmT, xm,
        4096, 1024, 1024, b_map, nullptr, nullptr, nullptr, nullptr);
    // G2: t1T = w1T @ xm^T  (M1024 N4096 K1024) -> [feat][node], coalesced
    gemm_mfma<1, 0, 1><<<dim3(32, 8, 1), 512, 0, stream>>>(w1T, xm, t1T,
        1024, 4096, 1024, nullptr, nullptr, nullptr, nullptr, nullptr);
    // G3: h1 = bn1(relu(AnT @ t1 + b1))  M4096 N1024 K4096, 256x128 2 blk/CU
    if (big) {
        gemm_big<256, 128, 4><<<dim3(8, 16, 4), 512, 0, stream>>>(AnT, t1T, P, 4096, 1024, 4096);
        reduce_k<2, 4, 1024><<<4096, 256, 0, stream>>>(P, h1, 4194304,
            b1, bn1_g, bn1_b, bn1_m, bn1_v);
    } else {
        gemm_big<256, 128, 2><<<dim3(8, 16, 2), 512, 0, stream>>>(AnT, t1T, P, 4096, 1024, 4096);
        reduce_k<2, 2, 1024><<<4096, 256, 0, stream>>>(P, h1, 4194304,
            b1, bn1_g, bn1_b, bn1_m, bn1_v);
    }
    // G4 (swapped): t2T = w2T @ h1^T     M512 N4096 K1024, 128^2 SK2 (2 blk/CU)
    gemm_mfma<0, 0, 2><<<dim3(32, 4, 2), 512, 0, stream>>>(w2T, h1, P,
        512, 4096, 1024, nullptr, nullptr, nullptr, nullptr, nullptr);
    reduce_k<0, 2, 1><<<2048, 256, 0, stream>>>(P, t2T, 2097152,
        nullptr, nullptr, nullptr, nullptr, nullptr);
    // G5 (swapped): t2T @ AnT^T          M512 N4096 K4096, 256x128 2 blk/CU
    if (big) {
        gemm_big<256, 128, 8><<<dim3(32, 2, 8), 512, 0, stream>>>(t2T, AnT, P, 512, 4096, 4096);
        reduce_pool_kernel<8><<<2048, 256, 0, stream>>>(
            P, pooled, b2, bn2_g, bn2_b, bn2_m, bn2_v);
    } else {
        gemm_big<256, 128, 4><<<dim3(32, 2, 4), 512, 0, stream>>>(t2T, AnT, P, 512, 4096, 4096);
        reduce_pool_kernel<4><<<2048, 256, 0, stream>>>(
            P, pooled, b2, bn2_g, bn2_b, bn2_m, bn2_v);
    }

    finalize_kernel<<<1, 512, 0, stream>>>(pooled, w_attn, b_attn, out);
}

// Round 10
// 293.916 us; speedup vs baseline: 1.1061x; 1.1061x over previous
//
#include <hip/hip_runtime.h>

#define NN 4096
#define R_RANK 10

typedef __bf16 bf16x8 __attribute__((ext_vector_type(8)));
typedef float floatx4 __attribute__((ext_vector_type(4)));

__device__ __forceinline__ unsigned short f2bf(float f) {
    union { float f; unsigned int u; } v; v.f = f;
    unsigned int r = v.u + 0x7FFFu + ((v.u >> 16) & 1u);   // RNE
    return (unsigned short)(r >> 16);
}
// async global->LDS, 16B per lane; LDS dest = wave-uniform base + lane*16
__device__ __forceinline__ void gll16(const void* g, void* l) {
    __builtin_amdgcn_global_load_lds(
        (const __attribute__((address_space(1))) unsigned int*)g,
        (__attribute__((address_space(3))) unsigned int*)l, 16, 0, 0);
}
template<int N>
__device__ __forceinline__ void wait_vm() {
    if constexpr (N == 0)       asm volatile("s_waitcnt vmcnt(0)" ::: "memory");
    else if constexpr (N == 3)  asm volatile("s_waitcnt vmcnt(3)" ::: "memory");
    else if constexpr (N == 4)  asm volatile("s_waitcnt vmcnt(4)" ::: "memory");
    else if constexpr (N == 6)  asm volatile("s_waitcnt vmcnt(6)" ::: "memory");
    else if constexpr (N == 8)  asm volatile("s_waitcnt vmcnt(8)" ::: "memory");
    else static_assert(N < 0, "add vmcnt literal");
}
#define SB __builtin_amdgcn_sched_barrier(0)

// ---------------------------------------------------------------------------
// Adjacency: row stats (4 rows/block; zeroes deg+pooled) -> col degree -> AnT
// ---------------------------------------------------------------------------
__global__ __launch_bounds__(256) void row_stats_kernel(
    const float* __restrict__ nv1, const float* __restrict__ nv2,
    float* __restrict__ rowmax, float* __restrict__ rowsum,
    float* __restrict__ deg, float* __restrict__ pooled)
{
    const int i0 = blockIdx.x * 4;
    const int tid = threadIdx.x;
    if (blockIdx.x < 16) deg[blockIdx.x * 256 + tid] = 0.f;
    if (blockIdx.x >= 16 && blockIdx.x < 18) pooled[(blockIdx.x - 16) * 256 + tid] = 0.f;
    __shared__ float a[4][R_RANK];
    if (tid < 4 * R_RANK) a[tid / R_RANK][tid % R_RANK] = nv1[i0 * R_RANK + tid];
    __syncthreads();

    float s[4][16];
    float mx[4] = {0.f, 0.f, 0.f, 0.f};   // relu >= 0
    #pragma unroll
    for (int t = 0; t < 16; ++t) {
        const int j = t * 256 + tid;
        float v[R_RANK];
        #pragma unroll
        for (int r = 0; r < R_RANK; ++r) v[r] = nv2[r * NN + j];
        #pragma unroll
        for (int q = 0; q < 4; ++q) {
            float acc = 0.f;
            #pragma unroll
            for (int r = 0; r < R_RANK; ++r) acc = fmaf(a[q][r], v[r], acc);
            acc = fmaxf(acc, 0.f);
            s[q][t] = acc;
            mx[q] = fmaxf(mx[q], acc);
        }
    }
    __shared__ float red[4][4];
    #pragma unroll
    for (int q = 0; q < 4; ++q) {
        float m = mx[q];
        #pragma unroll
        for (int off = 32; off > 0; off >>= 1) m = fmaxf(m, __shfl_down(m, off, 64));
        if ((tid & 63) == 0) red[q][tid >> 6] = m;
    }
    __syncthreads();
    #pragma unroll
    for (int q = 0; q < 4; ++q)
        mx[q] = fmaxf(fmaxf(red[q][0], red[q][1]), fmaxf(red[q][2], red[q][3]));
    __syncthreads();
    float sm[4] = {0.f, 0.f, 0.f, 0.f};
    #pragma unroll
    for (int t = 0; t < 16; ++t)
        #pragma unroll
        for (int q = 0; q < 4; ++q) sm[q] += __expf(s[q][t] - mx[q]);
    #pragma unroll
    for (int q = 0; q < 4; ++q) {
        float m = sm[q];
        #pragma unroll
        for (int off = 32; off > 0; off >>= 1) m += __shfl_down(m, off, 64);
        if ((tid & 63) == 0) red[q][tid >> 6] = m;
    }
    __syncthreads();
    if (tid < 4) {
        rowmax[i0 + tid] = mx[tid];
        rowsum[i0 + tid] = red[tid][0] + red[tid][1] + red[tid][2] + red[tid][3];
    }
}

// col degree: deg[j] += sum_{i in chunk} exp(relu(nv1_i . nv2_j) - rm_i)/rs_i
__global__ __launch_bounds__(256) void col_sum_kernel(
    const float* __restrict__ nv1, const float* __restrict__ nv2,
    const float* __restrict__ rowmax, const float* __restrict__ rowsum,
    float* __restrict__ deg)
{
    const int tid = threadIdx.x;
    const int j = blockIdx.x * 256 + tid;
    const int i0 = blockIdx.y * 64;
    __shared__ float a[64][R_RANK];
    __shared__ float rm[64], rs[64];
    if (tid < 64) {
        rm[tid] = rowmax[i0 + tid];
        rs[tid] = 1.0f / rowsum[i0 + tid];
    }
    for (int t = tid; t < 64 * R_RANK; t += 256)
        a[t / R_RANK][t % R_RANK] = nv1[i0 * R_RANK + t];
    __syncthreads();

    float v[R_RANK];
    #pragma unroll
    for (int r = 0; r < R_RANK; ++r) v[r] = nv2[r * NN + j];
    float acc = 0.f;
    #pragma unroll 4
    for (int t = 0; t < 64; ++t) {
        float s = 0.f;
        #pragma unroll
        for (int r = 0; r < R_RANK; ++r) s = fmaf(a[t][r], v[r], s);
        s = fmaxf(s, 0.f);
        acc += __expf(s - rm[t]) * rs[t];
    }
    atomicAdd(&deg[j], acc);
}

__global__ __launch_bounds__(256) void an_build_kernel(
    const float* __restrict__ nv1, const float* __restrict__ nv2,
    const float* __restrict__ rowmax, const float* __restrict__ rowsum,
    const float* __restrict__ deg, unsigned short* __restrict__ AnT)
{
    const int tid = threadIdx.x;
    const int j = blockIdx.x * 256 + tid;
    const int i0 = blockIdx.y * 8;
    __shared__ float v2s[8][R_RANK];
    __shared__ float dis[8];
    if (tid < 8 * R_RANK) {
        const int r = tid / 8, t = tid % 8;
        v2s[t][r] = nv2[r * NN + i0 + t];
    }
    if (tid < 8) dis[tid] = rsqrtf(1.0f + deg[i0 + tid]);

    float a[R_RANK];
    #pragma unroll
    for (int r = 0; r < R_RANK; ++r) a[r] = nv1[j * R_RANK + r];
    const float rm = rowmax[j];
    const float rs = 1.0f / rowsum[j];
    const float dj = rsqrtf(1.0f + deg[j]);
    __syncthreads();

    #pragma unroll
    for (int t = 0; t < 8; ++t) {
        const int i = i0 + t;
        float s = 0.f;
        #pragma unroll
        for (int r = 0; r < R_RANK; ++r) s = fmaf(a[r], v2s[t][r], s);
        s = fmaxf(s, 0.f);
        const float adp = __expf(s - rm) * rs;
        const float val = (adp + ((i == j) ? 1.f : 0.f)) * dis[t] * dj;
        AnT[(size_t)i * NN + j] = f2bf(val);
    }
}

// ---------------------------------------------------------------------------
// prep: z=0 w_map^T, z=1 w1^T, z=2 w2^T (fp32 -> bf16 transposed), z=3 cvt x
// ---------------------------------------------------------------------------
__global__ __launch_bounds__(256) void prep_kernel(
    const float* __restrict__ x, const float* __restrict__ w_map,
    const float* __restrict__ w1, const float* __restrict__ w2,
    unsigned short* __restrict__ xb, unsigned short* __restrict__ wmT,
    unsigned short* __restrict__ w1T, unsigned short* __restrict__ w2T)
{
    const int z = blockIdx.z;
    const int tid = threadIdx.x;
    if (z == 3) {
        const int b = blockIdx.x + blockIdx.y * 32;
        const size_t base = (size_t)b * 4096 + (size_t)tid * 16;
        #pragma unroll
        for (int i = 0; i < 2; ++i) {
            const float4 a0 = *(const float4*)(x + base + i * 8);
            const float4 a1 = *(const float4*)(x + base + i * 8 + 4);
            ushort4 p, q;
            p.x = f2bf(a0.x); p.y = f2bf(a0.y); p.z = f2bf(a0.z); p.w = f2bf(a0.w);
            q.x = f2bf(a1.x); q.y = f2bf(a1.y); q.z = f2bf(a1.z); q.w = f2bf(a1.w);
            *(ushort4*)(xb + base + i * 8) = p;
            *(ushort4*)(xb + base + i * 8 + 4) = q;
        }
        return;
    }
    const float* W = (z == 0) ? w_map : (z == 1) ? w1 : w2;
    unsigned short* WT = (z == 0) ? wmT : (z == 1) ? w1T : w2T;
    const int CN = (z == 2) ? 512 : 1024;
    if (blockIdx.x * 32 >= CN) return;
    __shared__ float s[32][33];
    const int tx = tid & 31, ty = tid >> 5;
    const int r0 = blockIdx.y * 32, c0 = blockIdx.x * 32;
    #pragma unroll
    for (int i = 0; i < 4; ++i)
        s[ty + 8 * i][tx] = W[(size_t)(r0 + ty + 8 * i) * CN + c0 + tx];
    __syncthreads();
    #pragma unroll
    for (int i = 0; i < 4; ++i)
        WT[(size_t)(c0 + ty + 8 * i) * 1024 + r0 + tx] = f2bf(s[tx][ty + 8 * i]);
}

// ---------------------------------------------------------------------------
// 128x128 bf16 MFMA GEMM (BK=64, 8 waves 2x4, 4x2 frags). 4 LDS buffers,
// DEPTH-2 prefetch, counted vmcnt, ONE raw barrier per tile (WAR-safe:
// STAGE(t+2) writes buf (t+2)&3; slowest concurrent reader is tile t-1 in
// buf (t+3)&3 -- disjoint). XCD-chunked swizzle.
// OUTM: 0 = fp32 P[z][M][N]; 1 = bf16 [M][N] fused epilogue.
// EPI (OUTM==1): 0 none, 1 relu(x+bias), 2 bn(relu(x+bias)) col-indexed.
// ---------------------------------------------------------------------------
template<int OUTM, int EPI, int SK>
__global__ __launch_bounds__(512) void gemm_mfma(
    const unsigned short* __restrict__ A, const unsigned short* __restrict__ Bt,
    void* __restrict__ Out, const int M, const int N, const int K,
    const float* __restrict__ bias, const float* __restrict__ gamma,
    const float* __restrict__ beta, const float* __restrict__ mean,
    const float* __restrict__ var)
{
    __shared__ __align__(16) unsigned short As[4][8192];
    __shared__ __align__(16) unsigned short Bs[4][8192];
    const int tid = threadIdx.x;
    const int l = tid & 63, w = tid >> 6;       // 8 waves
    const int wy = w >> 2, wx = w & 3;          // 2x4 wave grid, 64x32 per wave
    const int lr = l & 15, lq = l >> 4;

    // XCD-chunked bijective swizzle (nwg % 8 == 0)
    const int gx = gridDim.x, gy = gridDim.y;
    int lin = blockIdx.x + gx * (blockIdx.y + gy * blockIdx.z);
    const int q = (gx * gy * gridDim.z) >> 3;
    lin = (lin & 7) * q + (lin >> 3);
    const int bx = lin % gx;
    const int by = (lin / gx) % gy;
    const int bz = lin / (gx * gy);

    const int row0 = by * 128, col0 = bx * 128;
    const int Kc = K / SK;
    const int kb = bz * Kc;
    const int nt = Kc >> 6;                      // K-tiles of 64

    const unsigned short* Ag0 = A + (size_t)(row0 + w * 16 + lr) * K + kb + lq * 8;
    const unsigned short* Bg0 = Bt + (size_t)(col0 + w * 16 + lr) * K + kb + lq * 8;

    floatx4 acc[4][2];
    #pragma unroll
    for (int i = 0; i < 4; ++i)
        #pragma unroll
        for (int j = 0; j < 2; ++j) acc[i][j] = (floatx4){0.f, 0.f, 0.f, 0.f};

    #define STAGE(b, t)                                                         \
    {                                                                           \
        char* Aw = (char*)As[b] + w * 1024;                                     \
        char* Bw = (char*)Bs[b] + w * 1024;                                     \
        const int kk = (t) * 64;                                                \
        gll16(Ag0 + kk,      Aw);                                               \
        gll16(Ag0 + kk + 32, Aw + 8192);                                        \
        gll16(Bg0 + kk,      Bw);                                               \
        gll16(Bg0 + kk + 32, Bw + 8192);                                        \
    }

    STAGE(0, 0)
    STAGE(1, 1)
    for (int t = 0; t < nt; ++t) {
        if (t + 2 < nt) {
            STAGE((t + 2) & 3, t + 2)
            wait_vm<8>();                   // retire tile t's 4; t+1,t+2 fly
        } else if (t + 1 < nt) {
            wait_vm<4>();
        } else {
            wait_vm<0>();
        }
        SB; __builtin_amdgcn_s_barrier(); SB;   // buf t published (RAW)

        const char* Afr = (const char*)As[t & 3] + wy * 4096 + l * 16;
        const char* Bfr = (const char*)Bs[t & 3] + wx * 2048 + l * 16;
        #pragma unroll
        for (int h = 0; h < 2; ++h) {
            bf16x8 af[4], bf[2];
            #pragma unroll
            for (int i = 0; i < 4; ++i) af[i] = *(const bf16x8*)(Afr + h * 8192 + i * 1024);
            #pragma unroll
            for (int j = 0; j < 2; ++j) bf[j] = *(const bf16x8*)(Bfr + h * 8192 + j * 1024);
            #pragma unroll
            for (int mf = 0; mf < 4; ++mf)
                #pragma unroll
                for (int nf = 0; nf < 2; ++nf)
                    acc[mf][nf] = __builtin_amdgcn_mfma_f32_16x16x32_bf16(
                        af[mf], bf[nf], acc[mf][nf], 0, 0, 0);
        }
    }
    #undef STAGE

    const int gr0 = row0 + wy * 64 + lq * 4;
    const int gc0 = col0 + wx * 32 + lr;
    if constexpr (OUTM == 0) {
        float* Pz = (float*)Out + (size_t)bz * M * N;
        #pragma unroll
        for (int mf = 0; mf < 4; ++mf) {
            const int gr = gr0 + mf * 16;
            #pragma unroll
            for (int nf = 0; nf < 2; ++nf) {
                const int gc = gc0 + nf * 16;
                #pragma unroll
                for (int r = 0; r < 4; ++r)
                    Pz[(size_t)(gr + r) * N + gc] = acc[mf][nf][r];
            }
        }
    } else {
        unsigned short* O = (unsigned short*)Out;
        #pragma unroll
        for (int nf = 0; nf < 2; ++nf) {
            const int gc = gc0 + nf * 16;
            float bb = 0.f, sc = 1.f, sh = 0.f;
            if constexpr (EPI >= 1) bb = bias[gc];
            if constexpr (EPI == 2) {
                sc = gamma[gc] * rsqrtf(var[gc] + 1e-5f);
                sh = beta[gc] - mean[gc] * sc;
            }
            #pragma unroll
            for (int mf = 0; mf < 4; ++mf) {
                const int gr = gr0 + mf * 16;
                #pragma unroll
                for (int r = 0; r < 4; ++r) {
                    float xv = acc[mf][nf][r];
                    if constexpr (EPI >= 1) xv = fmaxf(xv + bb, 0.f);
                    if constexpr (EPI == 2) xv = fmaf(xv, sc, sh);
                    O[(size_t)(gr + r) * N + gc] = f2bf(xv);
                }
            }
        }
    }
}

// ---------------------------------------------------------------------------
// Big-tile bf16 MFMA GEMM, BM x BN, BK=32, 8 waves (2x4), per-wave
// (BM/2)x(BN/4). Frag-ordered conflict-free LDS, 4 buffers, DEPTH-2
// counted-vmcnt prefetch, ONE raw barrier per tile (WAR-safe by buffer
// distance, as in gemm_mfma). fp32 partials P[z][M][N]. XCD swizzle.
// ---------------------------------------------------------------------------
template<int BM, int BN, int SK>
__global__ __launch_bounds__(512, 1) void gemm_big(
    const unsigned short* __restrict__ A, const unsigned short* __restrict__ Bt,
    float* __restrict__ P, const int M, const int N, const int K)
{
    constexpr int MR = BM / 32;           // m-frags per wave
    constexpr int NRF = BN / 64;          // n-frags per wave
    constexpr int NA = BM / 128;          // A gll16 per wave per tile
    constexpr int NB = BN / 128;          // B gll16 per wave per tile
    constexpr int LPT = NA + NB;
    constexpr int ABYTES = BM * 64;       // bytes of A section per buffer
    __shared__ __align__(16) unsigned short L[4][(BM + BN) * 32];
    const int tid = threadIdx.x;
    const int l = tid & 63, w = tid >> 6;
    const int wy = w >> 2, wx = w & 3;
    const int lr = l & 15, lq = l >> 4;

    const int gx = gridDim.x, gy = gridDim.y;
    int lin = blockIdx.x + gx * (blockIdx.y + gy * blockIdx.z);
    const int q = (gx * gy * gridDim.z) >> 3;   // nwg % 8 == 0
    lin = (lin & 7) * q + (lin >> 3);
    const int bx = lin % gx;
    const int by = (lin / gx) % gy;
    const int bz = lin / (gx * gy);

    const int row0 = by * BM, col0 = bx * BN;
    const int Kc = K / SK, kb = bz * Kc;
    const int nt = Kc >> 5;                     // BK=32 tiles (>= 16 in all uses)

    const unsigned short* Ag = A + (size_t)(row0 + w * (BM / 8) + lr) * K + kb + lq * 8;
    const unsigned short* Bg = Bt + (size_t)(col0 + w * (BN / 8) + lr) * K + kb + lq * 8;

    floatx4 acc[MR][NRF];
    #pragma unroll
    for (int i = 0; i < MR; ++i)
        #pragma unroll
        for (int j = 0; j < NRF; ++j) acc[i][j] = (floatx4){0.f, 0.f, 0.f, 0.f};

    #define STAGEB(b, t)                                                        \
    {                                                                           \
        char* Ld = (char*)L[b];                                                 \
        const int kk = (t) * 32;                                                \
        _Pragma("unroll")                                                       \
        for (int s = 0; s < NA; ++s)                                            \
            gll16(Ag + (size_t)(s * 16) * K + kk, Ld + (w * NA + s) * 1024);    \
        _Pragma("unroll")                                                       \
        for (int s = 0; s < NB; ++s)                                            \
            gll16(Bg + (size_t)(s * 16) * K + kk,                               \
                  Ld + ABYTES + (w * NB + s) * 1024);                           \
    }

    STAGEB(0, 0)
    STAGEB(1, 1)
    for (int t = 0; t < nt; ++t) {
        if (t + 2 < nt) {
            STAGEB((t + 2) & 3, t + 2)
            wait_vm<2 * LPT>();                 // tile t retired; t+1,t+2 fly
        } else if (t + 1 < nt) {
            wait_vm<LPT>();
        } else {
            wait_vm<0>();
        }
        SB; __builtin_amdgcn_s_barrier(); SB;   // buf t&3 published (RAW)

        // A: wave-row wy owns MR 1KB chunks at wy*MR*1024; B: wx owns NRF
        const char* Ab = (const char*)L[t & 3] + wy * (MR * 1024) + l * 16;
        const char* Bb = (const char*)L[t & 3] + ABYTES + wx * (NRF * 1024) + l * 16;
        bf16x8 af[MR], bf[NRF];
        #pragma unroll
        for (int i = 0; i < MR; ++i) af[i] = *(const bf16x8*)(Ab + i * 1024);
        #pragma unroll
        for (int j = 0; j < NRF; ++j) bf[j] = *(const bf16x8*)(Bb + j * 1024);
        __builtin_amdgcn_s_setprio(1);
        #pragma unroll
        for (int mf = 0; mf < MR; ++mf)
            #pragma unroll
            for (int nf = 0; nf < NRF; ++nf)
                acc[mf][nf] = __builtin_amdgcn_mfma_f32_16x16x32_bf16(
                    af[mf], bf[nf], acc[mf][nf], 0, 0, 0);
        __builtin_amdgcn_s_setprio(0);
    }
    #undef STAGEB

    float* Pz = P + (size_t)bz * M * N;
    const int gr0 = row0 + wy * (BM / 2) + lq * 4;
    const int gc0 = col0 + wx * (BN / 4) + lr;
    #pragma unroll
    for (int mf = 0; mf < MR; ++mf) {
        const int gr = gr0 + mf * 16;
        #pragma unroll
        for (int nf = 0; nf < NRF; ++nf) {
            const int gc = gc0 + nf * 16;
            #pragma unroll
            for (int r = 0; r < 4; ++r)
                Pz[(size_t)(gr + r) * N + gc] = acc[mf][nf][r];
        }
    }
}

// ---------------------------------------------------------------------------
// Split-K reduce + epilogue -> bf16. EPI: 0 none, 2 bn(relu(x+b)) col-indexed.
// ---------------------------------------------------------------------------
template<int EPI, int S, int NC>
__global__ __launch_bounds__(256) void reduce_k(
    const float* __restrict__ P, unsigned short* __restrict__ out, const int MN,
    const float* __restrict__ bias, const float* __restrict__ gamma,
    const float* __restrict__ beta, const float* __restrict__ mean,
    const float* __restrict__ var)
{
    const int idx = blockIdx.x * 256 + threadIdx.x;   // float4 index
    const int n4 = MN >> 2;
    const float4* Pv = (const float4*)P;
    float4 v = Pv[idx];
    #pragma unroll
    for (int z = 1; z < S; ++z) {
        const float4 t = Pv[idx + (size_t)z * n4];
        v.x += t.x; v.y += t.y; v.z += t.z; v.w += t.w;
    }
    float vals[4] = {v.x, v.y, v.z, v.w};
    if constexpr (EPI >= 1) {
        const int c0 = (idx << 2) & (NC - 1);
        const float4 b4 = *(const float4*)(bias + c0);
        const float bb[4] = {b4.x, b4.y, b4.z, b4.w};
        float sc[4], sh[4];
        if constexpr (EPI == 2) {
            const float4 g4 = *(const float4*)(gamma + c0);
            const float4 e4 = *(const float4*)(beta + c0);
            const float4 m4 = *(const float4*)(mean + c0);
            const float4 v4 = *(const float4*)(var + c0);
            const float gg[4] = {g4.x, g4.y, g4.z, g4.w};
            const float ee[4] = {e4.x, e4.y, e4.z, e4.w};
            const float mm[4] = {m4.x, m4.y, m4.z, m4.w};
            const float vv[4] = {v4.x, v4.y, v4.z, v4.w};
            #pragma unroll
            for (int j = 0; j < 4; ++j) {
                sc[j] = gg[j] * rsqrtf(vv[j] + 1e-5f);
                sh[j] = ee[j] - mm[j] * sc[j];
            }
        }
        #pragma unroll
        for (int j = 0; j < 4; ++j) {
            float xv = fmaxf(vals[j] + bb[j], 0.f);
            if constexpr (EPI == 2) xv = fmaf(xv, sc[j], sh[j]);
            vals[j] = xv;
        }
    }
    ushort4 p;
    p.x = f2bf(vals[0]); p.y = f2bf(vals[1]); p.z = f2bf(vals[2]); p.w = f2bf(vals[3]);
    *(ushort4*)(out + ((size_t)idx << 2)) = p;
}

// ---------------------------------------------------------------------------
// Split-K reduce + bn2(relu(x+b)) + mean-pool (h2 never materialized).
// P[z][512][4096]; params row(=channel)-indexed; atomicAdd per-block sums.
// ---------------------------------------------------------------------------
template<int S>
__global__ __launch_bounds__(256) void reduce_pool_kernel(
    const float* __restrict__ P, float* __restrict__ pooled,
    const float* __restrict__ bias, const float* __restrict__ gamma,
    const float* __restrict__ beta, const float* __restrict__ mean,
    const float* __restrict__ var)
{
    const int idx = blockIdx.x * 256 + threadIdx.x;   // float4 index
    const int row = blockIdx.x >> 2;                  // 4096 floats = 1024 f4 per row
    constexpr int n4 = 512 * 4096 / 4;
    const float4* Pv = (const float4*)P;
    float4 v = Pv[idx];
    #pragma unroll
    for (int z = 1; z < S; ++z) {
        const float4 t = Pv[idx + (size_t)z * n4];
        v.x += t.x; v.y += t.y; v.z += t.z; v.w += t.w;
    }
    const float b0 = bias[row];
    const float sc = gamma[row] * rsqrtf(var[row] + 1e-5f);
    const float sh = beta[row] - mean[row] * sc;
    float s = 0.f;
    const float vals[4] = {v.x, v.y, v.z, v.w};
    #pragma unroll
    for (int j = 0; j < 4; ++j)
        s += fmaf(fmaxf(vals[j] + b0, 0.f), sc, sh);
    #pragma unroll
    for (int off = 32; off > 0; off >>= 1) s += __shfl_down(s, off, 64);
    __shared__ float red[4];
    if ((threadIdx.x & 63) == 0) red[threadIdx.x >> 6] = s;
    __syncthreads();
    if (threadIdx.x == 0)
        atomicAdd(&pooled[row], red[0] + red[1] + red[2] + red[3]);
}

__global__ __launch_bounds__(512) void finalize_kernel(
    const float* __restrict__ pooled, const float* __restrict__ w_attn,
    const float* __restrict__ b_attn, float* __restrict__ out)
{
    const int c = threadIdx.x;
    __shared__ float red[512];
    const float p = pooled[c] * (1.0f / 4096.0f);
    red[c] = p * w_attn[c];
    __syncthreads();
    for (int s = 256; s > 0; s >>= 1) {
        if (c < s) red[c] += red[c + s];
        __syncthreads();
    }
    const float attn = 1.0f / (1.0f + __expf(-(red[0] + b_attn[0])));
    out[c] = p * attn;
}

// ---------------------------------------------------------------------------
extern "C" void kernel_launch(void* const* d_in, const int* in_sizes, int n_in,
                              void* d_out, int out_size, void* d_ws, size_t ws_size,
                              hipStream_t stream) {
    const float* x      = (const float*)d_in[0];
    const float* w_map  = (const float*)d_in[1];
    const float* b_map  = (const float*)d_in[2];
    const float* nv1    = (const float*)d_in[3];
    const float* nv2    = (const float*)d_in[4];
    const float* w1     = (const float*)d_in[5];
    const float* b1     = (const float*)d_in[6];
    const float* w2     = (const float*)d_in[7];
    const float* b2     = (const float*)d_in[8];
    const float* bn1_g  = (const float*)d_in[9];
    const float* bn1_b  = (const float*)d_in[10];
    const float* bn1_m  = (const float*)d_in[11];
    const float* bn1_v  = (const float*)d_in[12];
    const float* bn2_g  = (const float*)d_in[13];
    const float* bn2_b  = (const float*)d_in[14];
    const float* bn2_m  = (const float*)d_in[15];
    const float* bn2_v  = (const float*)d_in[16];
    const float* w_attn = (const float*)d_in[17];
    const float* b_attn = (const float*)d_in[18];
    float* out = (float*)d_out;

    const size_t MB = 1024 * 1024;
    // big: P gets 64 MB (G3 256^2 SK4, G5 256^2 SK8); small: P 32 MB
    const bool big = ws_size >= 118 * MB;
    char* ws = (char*)d_ws;
    unsigned short* AnT = (unsigned short*)(ws);                  // [0,32M)
    float*          P   = (float*)(ws + 32 * MB);                 // 64M (big) / 32M
    char* B0 = big ? (ws + 96 * MB) : (ws + 64 * MB);
    unsigned short* xb  = (unsigned short*)(B0);                  // 8 MB, dead after G1
    unsigned short* t1T = (unsigned short*)(B0);                  //   reuse, dead after G3
    unsigned short* t2T = (unsigned short*)(B0);                  //   reuse after G3
    unsigned short* xm  = (unsigned short*)(B0 + 8 * MB);         // 8 MB, dead after G2
    unsigned short* h1  = (unsigned short*)(B0 + 8 * MB);         //   reuse, dead after G4
    unsigned short* wmT = (unsigned short*)(B0 + 16 * MB);        // 2 MB
    unsigned short* w1T = (unsigned short*)(B0 + 18 * MB);        // 2 MB
    unsigned short* w2T = (unsigned short*)(B0 + 20 * MB);        // 1 MB
    float* deg    = (float*)(B0 + 21 * MB);
    float* rowmax = deg + 4096;
    float* rowsum = rowmax + 4096;
    float* pooled = rowsum + 4096;

    // prep + adjacency
    prep_kernel<<<dim3(32, 32, 4), 256, 0, stream>>>(x, w_map, w1, w2, xb, wmT, w1T, w2T);
    row_stats_kernel<<<1024, 256, 0, stream>>>(nv1, nv2, rowmax, rowsum, deg, pooled);
    col_sum_kernel<<<dim3(16, 64), 256, 0, stream>>>(nv1, nv2, rowmax, rowsum, deg);
    an_build_kernel<<<dim3(16, 512), 256, 0, stream>>>(nv1, nv2, rowmax, rowsum, deg, AnT);

    // G1: xm = relu(x @ w_map + b_map)   M4096 N1024 K1024, fused epi
    gemm_mfma<1, 1, 1><<<dim3(8, 32, 1), 512, 0, stream>>>(xb, wmT, xm,
        4096, 1024, 1024, b_map, nullptr, nullptr, nullptr, nullptr);
    // G2: t1T = w1T @ xm^T  (M1024 N4096 K1024) -> [feat][node], coalesced
    gemm_mfma<1, 0, 1><<<dim3(32, 8, 1), 512, 0, stream>>>(w1T, xm, t1T,
        1024, 4096, 1024, nullptr, nullptr, nullptr, nullptr, nullptr);
    // G3: h1 = bn1(relu(AnT @ t1 + b1))  M4096 N1024 K4096, 256^2 tile
    if (big) {
        gemm_big<256, 256, 4><<<dim3(4, 16, 4), 512, 0, stream>>>(AnT, t1T, P, 4096, 1024, 4096);
        reduce_k<2, 4, 1024><<<4096, 256, 0, stream>>>(P, h1, 4194304,
            b1, bn1_g, bn1_b, bn1_m, bn1_v);
    } else {
        gemm_big<256, 128, 2><<<dim3(8, 16, 2), 512, 0, stream>>>(AnT, t1T, P, 4096, 1024, 4096);
        reduce_k<2, 2, 1024><<<4096, 256, 0, stream>>>(P, h1, 4194304,
            b1, bn1_g, bn1_b, bn1_m, bn1_v);
    }
    // G4 (swapped): t2T = w2T @ h1^T     M512 N4096 K1024, 128^2 SK2
    gemm_mfma<0, 0, 2><<<dim3(32, 4, 2), 512, 0, stream>>>(w2T, h1, P,
        512, 4096, 1024, nullptr, nullptr, nullptr, nullptr, nullptr);
    reduce_k<0, 2, 1><<<2048, 256, 0, stream>>>(P, t2T, 2097152,
        nullptr, nullptr, nullptr, nullptr, nullptr);
    // G5 (swapped): t2T @ AnT^T          M512 N4096 K4096, 256^2 tile
    if (big) {
        gemm_big<256, 256, 8><<<dim3(16, 2, 8), 512, 0, stream>>>(t2T, AnT, P, 512, 4096, 4096);
        reduce_pool_kernel<8><<<2048, 256, 0, stream>>>(
            P, pooled, b2, bn2_g, bn2_b, bn2_m, bn2_v);
    } else {
        gemm_big<256, 128, 4><<<dim3(32, 2, 4), 512, 0, stream>>>(t2T, AnT, P, 512, 4096, 4096);
        reduce_pool_kernel<4><<<2048, 256, 0, stream>>>(
            P, pooled, b2, bn2_g, bn2_b, bn2_m, bn2_v);
    }

    finalize_kernel<<<1, 512, 0, stream>>>(pooled, w_attn, b_attn, out);
}